// Round 2
// baseline (751.270 us; speedup 1.0000x reference)
//
#include <hip/hip_runtime.h>

#define M_ 8
#define B_ 64
#define S_ 128
#define D_ 512
#define H_ 8
#define FF_ 1024
#define HD_ 64

typedef __bf16 bf16x8 __attribute__((ext_vector_type(8)));
typedef float f32x4 __attribute__((ext_vector_type(4)));

__device__ __forceinline__ float bf2f(ushort u) {
    union { unsigned int i; float f; } x; x.i = ((unsigned int)u) << 16; return x.f;
}
__device__ __forceinline__ ushort f2bf(float f) {
    union { unsigned int i; float f; } x; x.f = f;
    unsigned int i = x.i;
    return (ushort)((i + 0x7FFFu + ((i >> 16) & 1u)) >> 16);
}
__device__ __forceinline__ void pack8(const float4 a, const float4 b, uint4* dst) {
    union { ushort u[8]; uint4 v; } t;
    t.u[0] = f2bf(a.x); t.u[1] = f2bf(a.y); t.u[2] = f2bf(a.z); t.u[3] = f2bf(a.w);
    t.u[4] = f2bf(b.x); t.u[5] = f2bf(b.y); t.u[6] = f2bf(b.z); t.u[7] = f2bf(b.w);
    *dst = t.v;
}

// ---------------------------------------------------------------------------
// 64x64-output-tile GEMM over K (fp32 X from global, fp32 W from global,
// converted to bf16 in registers; fp32 acc). 256 threads.
// Wave wv owns rows [16wv,16wv+16); acc[t] covers cols [16t,16t+16).
// LDS stride 40 shorts (80B): 16B-aligned b128 reads, conflict-free spans.
// ---------------------------------------------------------------------------
__device__ __forceinline__ void gemm64_fw(const float* __restrict__ X, int ldx,
                                          const float* __restrict__ Wc, int ldw,
                                          int K, short* Xs, short* Ws, f32x4* acc)
{
    const int tid = threadIdx.x, lane = tid & 63, wv = tid >> 6;
    const int c16 = lane & 15, koffs = (lane >> 4) * 8;
    const int xr = tid >> 2, xk = (tid & 3) * 8;
    const int wn = tid & 63, wk = (tid >> 6) * 8;
    for (int k0 = 0; k0 < K; k0 += 32) {
        const float* xp = X + xr * ldx + k0 + xk;
        pack8(*(const float4*)xp, *(const float4*)(xp + 4), (uint4*)&Xs[xr * 40 + xk]);
        const float* wp = Wc + (k0 + wk) * ldw + wn;
        union { ushort u[8]; uint4 v; } tw;
        #pragma unroll
        for (int j = 0; j < 8; ++j) tw.u[j] = f2bf(wp[j * ldw]);
        *(uint4*)&Ws[wn * 40 + wk] = tw.v;
        __syncthreads();
        bf16x8 a = *(const bf16x8*)&Xs[(16 * wv + c16) * 40 + koffs];
        #pragma unroll
        for (int t = 0; t < 4; ++t) {
            bf16x8 bfr = *(const bf16x8*)&Ws[(16 * t + c16) * 40 + koffs];
            acc[t] = __builtin_amdgcn_mfma_f32_16x16x32_bf16(a, bfr, acc[t], 0, 0, 0);
        }
        __syncthreads();
    }
}

// Same but X is a bf16 (ushort) workspace tensor.
__device__ __forceinline__ void gemm64_bw(const ushort* __restrict__ X, int ldx,
                                          const float* __restrict__ Wc, int ldw,
                                          int K, short* Xs, short* Ws, f32x4* acc)
{
    const int tid = threadIdx.x, lane = tid & 63, wv = tid >> 6;
    const int c16 = lane & 15, koffs = (lane >> 4) * 8;
    const int xr = tid >> 2, xk = (tid & 3) * 8;
    const int wn = tid & 63, wk = (tid >> 6) * 8;
    for (int k0 = 0; k0 < K; k0 += 32) {
        *(uint4*)&Xs[xr * 40 + xk] = *(const uint4*)&X[xr * ldx + k0 + xk];
        const float* wp = Wc + (k0 + wk) * ldw + wn;
        union { ushort u[8]; uint4 v; } tw;
        #pragma unroll
        for (int j = 0; j < 8; ++j) tw.u[j] = f2bf(wp[j * ldw]);
        *(uint4*)&Ws[wn * 40 + wk] = tw.v;
        __syncthreads();
        bf16x8 a = *(const bf16x8*)&Xs[(16 * wv + c16) * 40 + koffs];
        #pragma unroll
        for (int t = 0; t < 4; ++t) {
            bf16x8 bfr = *(const bf16x8*)&Ws[(16 * t + c16) * 40 + koffs];
            acc[t] = __builtin_amdgcn_mfma_f32_16x16x32_bf16(a, bfr, acc[t], 0, 0, 0);
        }
        __syncthreads();
    }
}

// ---------------------------------------------------------------------------
// Kernel 1: q = prev_query @ Wq + bq   [M,B,D] (bf16 to ws). grid (D/64, M)
// ---------------------------------------------------------------------------
__global__ __launch_bounds__(256) void k_qproj(const float* __restrict__ prev_query,
                                               const float* __restrict__ Wq,
                                               const float* __restrict__ bq,
                                               ushort* __restrict__ q_ws)
{
    __shared__ __align__(16) short Xs[64 * 40];
    __shared__ __align__(16) short Ws[64 * 40];
    const int cb = blockIdx.x, m = blockIdx.y;
    f32x4 acc[4] = {};
    gemm64_fw(prev_query + m * B_ * D_, D_, Wq + m * D_ * D_ + cb * 64, D_, D_, Xs, Ws, acc);
    const int lane = threadIdx.x & 63, wv = threadIdx.x >> 6;
    #pragma unroll
    for (int t = 0; t < 4; ++t)
        #pragma unroll
        for (int r = 0; r < 4; ++r) {
            int row = 16 * wv + (lane >> 4) * 4 + r;
            int col = cb * 64 + 16 * t + (lane & 15);
            q_ws[(m * B_ + row) * D_ + col] = f2bf(acc[t][r] + bq[m * D_ + col]);
        }
}

// ---------------------------------------------------------------------------
// Kernel 2: fused K/V projection + single-query attention per (m,b,h).
// grid (H, B, M), 256 threads. Wave owns rows [32w,32w+32) of S=128.
// ---------------------------------------------------------------------------
__global__ __launch_bounds__(256) void k_attn(const float* __restrict__ key_in,
                                              const float* __restrict__ value_in,
                                              const float* __restrict__ Wk,
                                              const float* __restrict__ Wv,
                                              const float* __restrict__ bk,
                                              const float* __restrict__ bv,
                                              const ushort* __restrict__ q_ws,
                                              ushort* __restrict__ ao_ws)
{
    const int h = blockIdx.x, b = blockIdx.y, m = blockIdx.z;
    __shared__ __align__(16) short smem[16896];   // phase A: staging; phase B: khs/vhs
    __shared__ float qv[HD_];
    __shared__ float sc[S_];
    __shared__ float red[256];
    __shared__ float sinv;
    short* Xk  = smem;            // [128*40]
    short* Xv  = smem + 5120;
    short* Wkt = smem + 10240;    // [64*40]
    short* Wvt = smem + 12800;
    short* khs = smem;            // [128*66] bf16 (after barrier)
    short* vhs = smem + 8448;

    const int tid = threadIdx.x, lane = tid & 63, wv = tid >> 6;
    const int c16 = lane & 15, koffs = (lane >> 4) * 8;
    const int ldx = B_ * D_;
    const float* kin = key_in + b * D_;
    const float* vin = value_in + b * D_;
    const float* Wkc = Wk + m * D_ * D_ + h * HD_;
    const float* Wvc = Wv + m * D_ * D_ + h * HD_;
    const int wn = tid & 63, wk = (tid >> 6) * 8;

    f32x4 ak[2][4] = {}, av[2][4] = {};
    for (int k0 = 0; k0 < D_; k0 += 32) {
        #pragma unroll
        for (int e = 0; e < 2; ++e) {
            int idx = tid + e * 256;
            int row = idx >> 2, kf = (idx & 3) * 8;
            const float* kp2 = kin + row * ldx + k0 + kf;
            const float* vp2 = vin + row * ldx + k0 + kf;
            pack8(*(const float4*)kp2, *(const float4*)(kp2 + 4), (uint4*)&Xk[row * 40 + kf]);
            pack8(*(const float4*)vp2, *(const float4*)(vp2 + 4), (uint4*)&Xv[row * 40 + kf]);
        }
        union { ushort u[8]; uint4 v; } tk, tv;
        const float* kp = Wkc + (k0 + wk) * D_ + wn;
        const float* vp = Wvc + (k0 + wk) * D_ + wn;
        #pragma unroll
        for (int j = 0; j < 8; ++j) { tk.u[j] = f2bf(kp[j * D_]); tv.u[j] = f2bf(vp[j * D_]); }
        *(uint4*)&Wkt[wn * 40 + wk] = tk.v;
        *(uint4*)&Wvt[wn * 40 + wk] = tv.v;
        __syncthreads();
        bf16x8 fak[2], fav[2];
        #pragma unroll
        for (int p = 0; p < 2; ++p) {
            fak[p] = *(const bf16x8*)&Xk[(32 * wv + 16 * p + c16) * 40 + koffs];
            fav[p] = *(const bf16x8*)&Xv[(32 * wv + 16 * p + c16) * 40 + koffs];
        }
        #pragma unroll
        for (int t = 0; t < 4; ++t) {
            bf16x8 fbk = *(const bf16x8*)&Wkt[(16 * t + c16) * 40 + koffs];
            bf16x8 fbv = *(const bf16x8*)&Wvt[(16 * t + c16) * 40 + koffs];
            #pragma unroll
            for (int p = 0; p < 2; ++p) {
                ak[p][t] = __builtin_amdgcn_mfma_f32_16x16x32_bf16(fak[p], fbk, ak[p][t], 0, 0, 0);
                av[p][t] = __builtin_amdgcn_mfma_f32_16x16x32_bf16(fav[p], fbv, av[p][t], 0, 0, 0);
            }
        }
        __syncthreads();
    }
    // write kh/vh tiles (+bias) to LDS, stride 66 to dodge bank conflicts
    #pragma unroll
    for (int p = 0; p < 2; ++p)
        #pragma unroll
        for (int t = 0; t < 4; ++t)
            #pragma unroll
            for (int r = 0; r < 4; ++r) {
                int row = 32 * wv + 16 * p + (lane >> 4) * 4 + r;
                int col = 16 * t + c16;
                khs[row * 66 + col] = (short)f2bf(ak[p][t][r] + bk[m * D_ + h * HD_ + col]);
                vhs[row * 66 + col] = (short)f2bf(av[p][t][r] + bv[m * D_ + h * HD_ + col]);
            }
    if (tid < HD_) qv[tid] = bf2f(q_ws[(m * B_ + b) * D_ + h * HD_ + tid]);
    __syncthreads();
    // scores
    if (tid < S_) {
        float s = 0.f;
        #pragma unroll 8
        for (int d = 0; d < HD_; ++d) s += qv[d] * bf2f((ushort)khs[tid * 66 + d]);
        sc[tid] = s * 0.125f;
    }
    __syncthreads();
    // softmax over 128 by wave 0
    if (tid < 64) {
        float s1 = sc[tid], s2 = sc[tid + 64];
        float mx = fmaxf(s1, s2);
        #pragma unroll
        for (int off = 32; off >= 1; off >>= 1) mx = fmaxf(mx, __shfl_xor(mx, off, 64));
        float e1 = __expf(s1 - mx), e2 = __expf(s2 - mx);
        sc[tid] = e1; sc[tid + 64] = e2;
        float sm = e1 + e2;
        #pragma unroll
        for (int off = 32; off >= 1; off >>= 1) sm += __shfl_xor(sm, off, 64);
        if (tid == 0) sinv = 1.0f / sm;
    }
    __syncthreads();
    // weighted sum of vh
    {
        int d = tid & 63, half = tid >> 6;
        float p = 0.f;
        #pragma unroll 8
        for (int j = 0; j < 32; ++j) {
            int s = half * 32 + j;
            p += sc[s] * bf2f((ushort)vhs[s * 66 + d]);
        }
        red[half * 64 + d] = p;
    }
    __syncthreads();
    if (tid < 64) {
        float o = (red[tid] + red[64 + tid] + red[128 + tid] + red[192 + tid]) * sinv;
        ao_ws[(m * B_ + b) * D_ + h * HD_ + tid] = f2bf(o);
    }
}

// ---------------------------------------------------------------------------
// Kernel 3: attn_out = ao @ Wo + bo; x = relu([attn_out, prev_state]) -> x_ws
// grid (D/64, M)
// ---------------------------------------------------------------------------
__global__ __launch_bounds__(256) void k_oproj(const ushort* __restrict__ ao_ws,
                                               const float* __restrict__ Wo,
                                               const float* __restrict__ bo,
                                               const float* __restrict__ prev_state,
                                               ushort* __restrict__ x_ws)
{
    __shared__ __align__(16) short Xs[64 * 40];
    __shared__ __align__(16) short Ws[64 * 40];
    const int cb = blockIdx.x, m = blockIdx.y;
    // second half of x: relu(prev_state) for our column slice, fp32 -> bf16
    #pragma unroll
    for (int e = 0; e < 2; ++e) {
        int idx = threadIdx.x + e * 256;          // 0..511
        int row = idx >> 3, koff = (idx & 7) * 8; // 64 rows x 64 cols / 8
        const float* pp = prev_state + (m * B_ + row) * D_ + cb * 64 + koff;
        float4 a = *(const float4*)pp, b = *(const float4*)(pp + 4);
        a.x = fmaxf(a.x, 0.f); a.y = fmaxf(a.y, 0.f); a.z = fmaxf(a.z, 0.f); a.w = fmaxf(a.w, 0.f);
        b.x = fmaxf(b.x, 0.f); b.y = fmaxf(b.y, 0.f); b.z = fmaxf(b.z, 0.f); b.w = fmaxf(b.w, 0.f);
        pack8(a, b, (uint4*)&x_ws[(m * B_ + row) * (2 * D_) + D_ + cb * 64 + koff]);
    }
    f32x4 acc[4] = {};
    gemm64_bw(ao_ws + m * B_ * D_, D_, Wo + m * D_ * D_ + cb * 64, D_, D_, Xs, Ws, acc);
    const int lane = threadIdx.x & 63, wv = threadIdx.x >> 6;
    #pragma unroll
    for (int t = 0; t < 4; ++t)
        #pragma unroll
        for (int r = 0; r < 4; ++r) {
            int row = 16 * wv + (lane >> 4) * 4 + r;
            int col = cb * 64 + 16 * t + (lane & 15);
            float v = fmaxf(acc[t][r] + bo[m * D_ + col], 0.0f);
            x_ws[(m * B_ + row) * (2 * D_) + col] = f2bf(v);
        }
}

// ---------------------------------------------------------------------------
// Kernel 4: h = relu(x@W1+b1), hg = relu(x@Wg1+bg1). grid (FF/64, M, 8) z=(g<<1)|mat
// ---------------------------------------------------------------------------
__global__ __launch_bounds__(256) void k_mlp1(const ushort* __restrict__ x_ws,
                                              const float* __restrict__ W1,
                                              const float* __restrict__ b1,
                                              const float* __restrict__ Wg1,
                                              const float* __restrict__ bg1,
                                              ushort* __restrict__ h_ws,
                                              ushort* __restrict__ hg_ws)
{
    __shared__ __align__(16) short Xs[64 * 40];
    __shared__ __align__(16) short Ws[64 * 40];
    const int cb = blockIdx.x, m = blockIdx.y;
    const int g = blockIdx.z >> 1, mat = blockIdx.z & 1;
    const int gm = g * M_ + m;
    const float* W = mat ? Wg1 : W1;
    const float* bb = mat ? bg1 : b1;
    ushort* outp = mat ? hg_ws : h_ws;
    f32x4 acc[4] = {};
    gemm64_bw(x_ws + m * B_ * 2 * D_, 2 * D_, W + gm * 2 * D_ * FF_ + cb * 64, FF_,
              2 * D_, Xs, Ws, acc);
    const int lane = threadIdx.x & 63, wv = threadIdx.x >> 6;
    #pragma unroll
    for (int t = 0; t < 4; ++t)
        #pragma unroll
        for (int r = 0; r < 4; ++r) {
            int row = 16 * wv + (lane >> 4) * 4 + r;
            int col = cb * 64 + 16 * t + (lane & 15);
            float v = fmaxf(acc[t][r] + bb[gm * FF_ + col], 0.0f);
            outp[(gm * B_ + row) * FF_ + col] = f2bf(v);
        }
}

// ---------------------------------------------------------------------------
// Kernel 5: g = sigmoid(hg . Wg2 + bg2). grid (32) = (g,m); 4 partials per b.
// ---------------------------------------------------------------------------
__global__ __launch_bounds__(256) void k_gate(const ushort* __restrict__ hg_ws,
                                              const float* __restrict__ Wg2,
                                              const float* __restrict__ bg2,
                                              float* __restrict__ g_ws)
{
    const int gm = blockIdx.x;   // g*8+m
    const int tid = threadIdx.x, b = tid >> 2, q = tid & 3;
    const ushort* hp = hg_ws + (gm * B_ + b) * FF_ + q * 256;
    const float* wp = Wg2 + gm * FF_ + q * 256;
    float s = 0.f;
    for (int j = 0; j < 256; j += 8) {
        union { ushort u[8]; uint4 v; } a;
        a.v = *(const uint4*)&hp[j];
        float4 w0 = *(const float4*)&wp[j], w1 = *(const float4*)&wp[j + 4];
        s += bf2f(a.u[0]) * w0.x + bf2f(a.u[1]) * w0.y + bf2f(a.u[2]) * w0.z + bf2f(a.u[3]) * w0.w
           + bf2f(a.u[4]) * w1.x + bf2f(a.u[5]) * w1.y + bf2f(a.u[6]) * w1.z + bf2f(a.u[7]) * w1.w;
    }
    __shared__ float red[256];
    red[b * 4 + q] = s;
    __syncthreads();
    if (tid < 64) {
        float t = red[tid * 4] + red[tid * 4 + 1] + red[tid * 4 + 2] + red[tid * 4 + 3]
                + bg2[gm];
        g_ws[gm * B_ + tid] = 1.0f / (1.0f + __expf(-t));
    }
}

// ---------------------------------------------------------------------------
// Kernel 6: out = tanh(relu(h@W2+b2)); new = g*out + (1-g)*prev; permuted store.
// grid (D/64, M, 4) z=g. Output slot: g -> (g+1)&3  (query->1,key->2,value->3,state->0)
// ---------------------------------------------------------------------------
__global__ __launch_bounds__(256) void k_mlp2(const ushort* __restrict__ h_ws,
                                              const float* __restrict__ W2,
                                              const float* __restrict__ b2,
                                              const float* __restrict__ g_ws,
                                              const float* __restrict__ prev_state,
                                              const float* __restrict__ prev_query,
                                              const float* __restrict__ prev_key,
                                              const float* __restrict__ prev_value,
                                              float* __restrict__ outp)
{
    __shared__ __align__(16) short Xs[64 * 40];
    __shared__ __align__(16) short Ws[64 * 40];
    const int cb = blockIdx.x, m = blockIdx.y, g = blockIdx.z;
    const int gm = g * M_ + m;
    f32x4 acc[4] = {};
    gemm64_bw(h_ws + gm * B_ * FF_, FF_, W2 + gm * FF_ * D_ + cb * 64, D_, FF_, Xs, Ws, acc);
    const float* prev = (g == 0) ? prev_query : (g == 1) ? prev_key
                      : (g == 2) ? prev_value : prev_state;
    const int slot = (g + 1) & 3;
    const int lane = threadIdx.x & 63, wv = threadIdx.x >> 6;
    #pragma unroll
    for (int t = 0; t < 4; ++t)
        #pragma unroll
        for (int r = 0; r < 4; ++r) {
            int row = 16 * wv + (lane >> 4) * 4 + r;
            int col = cb * 64 + 16 * t + (lane & 15);
            float v = tanhf(fmaxf(acc[t][r] + b2[gm * D_ + col], 0.0f));
            float gg = g_ws[gm * B_ + row];
            float pv = prev[(m * B_ + row) * D_ + col];
            outp[((slot * M_ + m) * B_ + row) * D_ + col] = gg * v + (1.0f - gg) * pv;
        }
}

// ---------------------------------------------------------------------------
extern "C" void kernel_launch(void* const* d_in, const int* in_sizes, int n_in,
                              void* d_out, int out_size, void* d_ws, size_t ws_size,
                              hipStream_t stream)
{
    (void)in_sizes; (void)n_in; (void)out_size; (void)ws_size;
    const float* prev_state = (const float*)d_in[0];
    const float* prev_query = (const float*)d_in[1];
    const float* prev_key   = (const float*)d_in[2];
    const float* prev_value = (const float*)d_in[3];
    const float* key_in     = (const float*)d_in[4];
    const float* value_in   = (const float*)d_in[5];
    const float* Wq  = (const float*)d_in[6];
    const float* bq  = (const float*)d_in[7];
    const float* Wk  = (const float*)d_in[8];
    const float* bk  = (const float*)d_in[9];
    const float* Wv  = (const float*)d_in[10];
    const float* bv  = (const float*)d_in[11];
    const float* Wo  = (const float*)d_in[12];
    const float* bo  = (const float*)d_in[13];
    const float* W1  = (const float*)d_in[14];
    const float* b1  = (const float*)d_in[15];
    const float* W2  = (const float*)d_in[16];
    const float* b2  = (const float*)d_in[17];
    const float* Wg1 = (const float*)d_in[18];
    const float* bg1 = (const float*)d_in[19];
    const float* Wg2 = (const float*)d_in[20];
    const float* bg2 = (const float*)d_in[21];
    float* outp = (float*)d_out;

    char* ws = (char*)d_ws;
    ushort* q_ws  = (ushort*)(ws);                        // 512 KB
    ushort* ao_ws = (ushort*)(ws + (512u << 10));         // 512 KB
    ushort* x_ws  = (ushort*)(ws + (1024u << 10));        // 1 MB
    ushort* h_ws  = (ushort*)(ws + (2048u << 10));        // 4 MB
    ushort* hg_ws = (ushort*)(ws + (6144u << 10));        // 4 MB
    float*  g_ws  = (float*) (ws + (10240u << 10));       // 8 KB

    k_qproj<<<dim3(8, 8), 256, 0, stream>>>(prev_query, Wq, bq, q_ws);
    k_attn <<<dim3(8, 64, 8), 256, 0, stream>>>(key_in, value_in, Wk, Wv, bk, bv, q_ws, ao_ws);
    k_oproj<<<dim3(8, 8), 256, 0, stream>>>(ao_ws, Wo, bo, prev_state, x_ws);
    k_mlp1 <<<dim3(16, 8, 8), 256, 0, stream>>>(x_ws, W1, b1, Wg1, bg1, h_ws, hg_ws);
    k_gate <<<dim3(32), 256, 0, stream>>>(hg_ws, Wg2, bg2, g_ws);
    k_mlp2 <<<dim3(8, 8, 4), 256, 0, stream>>>(h_ws, W2, b2, g_ws,
                                               prev_state, prev_query, prev_key, prev_value, outp);
}

// Round 3
// 519.038 us; speedup vs baseline: 1.4474x; 1.4474x over previous
//
#include <hip/hip_runtime.h>

#define M_ 8
#define B_ 64
#define S_ 128
#define D_ 512
#define H_ 8
#define FF_ 1024
#define HD_ 64

typedef __bf16 bf16x8 __attribute__((ext_vector_type(8)));
typedef float f32x4 __attribute__((ext_vector_type(4)));

__device__ __forceinline__ float bf2f(ushort u) {
    union { unsigned int i; float f; } x; x.i = ((unsigned int)u) << 16; return x.f;
}
__device__ __forceinline__ ushort f2bf(float f) {
    union { unsigned int i; float f; } x; x.f = f;
    unsigned int i = x.i;
    return (ushort)((i + 0x7FFFu + ((i >> 16) & 1u)) >> 16);
}
__device__ __forceinline__ void pack8(const float4 a, const float4 b, uint4* dst) {
    union { ushort u[8]; uint4 v; } t;
    t.u[0] = f2bf(a.x); t.u[1] = f2bf(a.y); t.u[2] = f2bf(a.z); t.u[3] = f2bf(a.w);
    t.u[4] = f2bf(b.x); t.u[5] = f2bf(b.y); t.u[6] = f2bf(b.z); t.u[7] = f2bf(b.w);
    *dst = t.v;
}

// ---------------------------------------------------------------------------
// 64x64-output-tile GEMM over K (fp32 X from global, fp32 W from global,
// converted to bf16 in registers; fp32 acc). 256 threads.
// ---------------------------------------------------------------------------
__device__ __forceinline__ void gemm64_fw(const float* __restrict__ X, int ldx,
                                          const float* __restrict__ Wc, int ldw,
                                          int K, short* Xs, short* Ws, f32x4* acc)
{
    const int tid = threadIdx.x, lane = tid & 63, wv = tid >> 6;
    const int c16 = lane & 15, koffs = (lane >> 4) * 8;
    const int xr = tid >> 2, xk = (tid & 3) * 8;
    const int wn = tid & 63, wk = (tid >> 6) * 8;
    for (int k0 = 0; k0 < K; k0 += 32) {
        const float* xp = X + xr * ldx + k0 + xk;
        pack8(*(const float4*)xp, *(const float4*)(xp + 4), (uint4*)&Xs[xr * 40 + xk]);
        const float* wp = Wc + (k0 + wk) * ldw + wn;
        union { ushort u[8]; uint4 v; } tw;
        #pragma unroll
        for (int j = 0; j < 8; ++j) tw.u[j] = f2bf(wp[j * ldw]);
        *(uint4*)&Ws[wn * 40 + wk] = tw.v;
        __syncthreads();
        bf16x8 a = *(const bf16x8*)&Xs[(16 * wv + c16) * 40 + koffs];
        #pragma unroll
        for (int t = 0; t < 4; ++t) {
            bf16x8 bfr = *(const bf16x8*)&Ws[(16 * t + c16) * 40 + koffs];
            acc[t] = __builtin_amdgcn_mfma_f32_16x16x32_bf16(a, bfr, acc[t], 0, 0, 0);
        }
        __syncthreads();
    }
}

// Same but X is a bf16 (ushort) workspace tensor.
__device__ __forceinline__ void gemm64_bw(const ushort* __restrict__ X, int ldx,
                                          const float* __restrict__ Wc, int ldw,
                                          int K, short* Xs, short* Ws, f32x4* acc)
{
    const int tid = threadIdx.x, lane = tid & 63, wv = tid >> 6;
    const int c16 = lane & 15, koffs = (lane >> 4) * 8;
    const int xr = tid >> 2, xk = (tid & 3) * 8;
    const int wn = tid & 63, wk = (tid >> 6) * 8;
    for (int k0 = 0; k0 < K; k0 += 32) {
        *(uint4*)&Xs[xr * 40 + xk] = *(const uint4*)&X[xr * ldx + k0 + xk];
        const float* wp = Wc + (k0 + wk) * ldw + wn;
        union { ushort u[8]; uint4 v; } tw;
        #pragma unroll
        for (int j = 0; j < 8; ++j) tw.u[j] = f2bf(wp[j * ldw]);
        *(uint4*)&Ws[wn * 40 + wk] = tw.v;
        __syncthreads();
        bf16x8 a = *(const bf16x8*)&Xs[(16 * wv + c16) * 40 + koffs];
        #pragma unroll
        for (int t = 0; t < 4; ++t) {
            bf16x8 bfr = *(const bf16x8*)&Ws[(16 * t + c16) * 40 + koffs];
            acc[t] = __builtin_amdgcn_mfma_f32_16x16x32_bf16(a, bfr, acc[t], 0, 0, 0);
        }
        __syncthreads();
    }
}

// ---------------------------------------------------------------------------
// Kernel 1: q = prev_query @ Wq + bq   [M,B,D] (bf16 to ws). grid (D/64, M)
// ---------------------------------------------------------------------------
__global__ __launch_bounds__(256) void k_qproj(const float* __restrict__ prev_query,
                                               const float* __restrict__ Wq,
                                               const float* __restrict__ bq,
                                               ushort* __restrict__ q_ws)
{
    __shared__ __align__(16) short Xs[64 * 40];
    __shared__ __align__(16) short Ws[64 * 40];
    const int cb = blockIdx.x, m = blockIdx.y;
    f32x4 acc[4] = {};
    gemm64_fw(prev_query + m * B_ * D_, D_, Wq + m * D_ * D_ + cb * 64, D_, D_, Xs, Ws, acc);
    const int lane = threadIdx.x & 63, wv = threadIdx.x >> 6;
    #pragma unroll
    for (int t = 0; t < 4; ++t)
        #pragma unroll
        for (int r = 0; r < 4; ++r) {
            int row = 16 * wv + (lane >> 4) * 4 + r;
            int col = cb * 64 + 16 * t + (lane & 15);
            q_ws[(m * B_ + row) * D_ + col] = f2bf(acc[t][r] + bq[m * D_ + col]);
        }
}

// ---------------------------------------------------------------------------
// Kernel 2: q~[mh, b, k] = sum_j qh[m,b,h*64+j] * Wk[m][k, h*64+j]
// (project query through Wk^T; bk drops out of softmax). grid (8 kb, H, M).
// Out tile 64(b) x 64(k), K=64.
// ---------------------------------------------------------------------------
__global__ __launch_bounds__(256) void k_qtilde(const ushort* __restrict__ q_ws,
                                                const float* __restrict__ Wk,
                                                ushort* __restrict__ qt_ws)
{
    const int kb = blockIdx.x, h = blockIdx.y, m = blockIdx.z;
    __shared__ __align__(16) short As[64 * 72];
    __shared__ __align__(16) short Ws[64 * 72];
    const int tid = threadIdx.x, lane = tid & 63, wv = tid >> 6;
    {   // stage A = qh [b=64][j=64]
        int r = lane, jj = wv * 16;
        const ushort* src = q_ws + (m * B_ + r) * D_ + h * HD_ + jj;
        *(uint4*)&As[r * 72 + jj]     = *(const uint4*)src;
        *(uint4*)&As[r * 72 + jj + 8] = *(const uint4*)(src + 8);
    }
    {   // stage B[j][n=k] = Wk[m][kb*64+n, h*64+j]  (row-major read, vectorized)
        int n = lane, jj = wv * 16;
        const float* src = Wk + m * D_ * D_ + (kb * 64 + n) * D_ + h * HD_ + jj;
        pack8(*(const float4*)src, *(const float4*)(src + 4), (uint4*)&Ws[n * 72 + jj]);
        pack8(*(const float4*)(src + 8), *(const float4*)(src + 12), (uint4*)&Ws[n * 72 + jj + 8]);
    }
    __syncthreads();
    const int c16 = lane & 15, koffs = (lane >> 4) * 8;
    f32x4 acc[4] = {};
    #pragma unroll
    for (int j0 = 0; j0 < 64; j0 += 32) {
        bf16x8 a = *(const bf16x8*)&As[(16 * wv + c16) * 72 + j0 + koffs];
        #pragma unroll
        for (int t = 0; t < 4; ++t) {
            bf16x8 bfr = *(const bf16x8*)&Ws[(16 * t + c16) * 72 + j0 + koffs];
            acc[t] = __builtin_amdgcn_mfma_f32_16x16x32_bf16(a, bfr, acc[t], 0, 0, 0);
        }
    }
    const int mh = m * H_ + h;
    #pragma unroll
    for (int t = 0; t < 4; ++t)
        #pragma unroll
        for (int r = 0; r < 4; ++r) {
            int row = 16 * wv + (lane >> 4) * 4 + r;     // b
            int col = kb * 64 + 16 * t + (lane & 15);    // k
            qt_ws[(mh * B_ + row) * D_ + col] = f2bf(acc[t][r]);
        }
}

// ---------------------------------------------------------------------------
// Kernel 3: per (b, half): scores[mh, s] = q~[mh,b,:].key_in[s,b,:]/8 ->
// softmax over s -> v~[mh, k] = sum_s w[mh,s] * value_in[s,b,k]. grid (2, B).
// 32 mh-rows per block. LDS ~79 KB -> 2 blocks/CU.
// ---------------------------------------------------------------------------
__global__ __launch_bounds__(256) void k_attn2(const float* __restrict__ key_in,
                                               const float* __restrict__ value_in,
                                               const ushort* __restrict__ qt_ws,
                                               ushort* __restrict__ vt_ws)
{
    const int half = blockIdx.x, b = blockIdx.y;
    const int mh0 = half * 32;
    __shared__ __align__(16) short As[32 * 40];
    __shared__ __align__(16) short Ks[128 * 40];
    __shared__ __align__(16) short Vs[512 * 40];
    __shared__ float scs[32 * 132];
    __shared__ __align__(16) short wbuf[32 * 136];
    const int tid = threadIdx.x, lane = tid & 63, wv = tid >> 6;
    const int c16 = lane & 15, koffs = (lane >> 4) * 8;
    const int wr = wv >> 1, wc = wv & 1;
    const int BD = B_ * D_;

    // ---- phase 1: scores GEMM, out [32 mh x 128 s], K = 512 ----
    f32x4 acc[4] = {};
    for (int k0 = 0; k0 < D_; k0 += 32) {
        {   // A-chunk: q~ rows mh0..+32, cols k0..+32
            int r = tid >> 3, kk = (tid & 7) * 4;
            *(uint2*)&As[r * 40 + kk] =
                *(const uint2*)&qt_ws[((mh0 + r) * B_ + b) * D_ + k0 + kk];
        }
        {   // key chunk: Ks[s][kk] = key_in[s, b, k0+kk]
            int s = tid >> 1, kk = (tid & 1) * 16;
            const float* src = key_in + s * BD + b * D_ + k0 + kk;
            pack8(*(const float4*)src, *(const float4*)(src + 4), (uint4*)&Ks[s * 40 + kk]);
            pack8(*(const float4*)(src + 8), *(const float4*)(src + 12), (uint4*)&Ks[s * 40 + kk + 8]);
        }
        __syncthreads();
        bf16x8 a = *(const bf16x8*)&As[(16 * wr + c16) * 40 + koffs];
        #pragma unroll
        for (int t = 0; t < 4; ++t) {
            bf16x8 kf = *(const bf16x8*)&Ks[(64 * wc + 16 * t + c16) * 40 + koffs];
            acc[t] = __builtin_amdgcn_mfma_f32_16x16x32_bf16(a, kf, acc[t], 0, 0, 0);
        }
        __syncthreads();
    }
    #pragma unroll
    for (int t = 0; t < 4; ++t)
        #pragma unroll
        for (int r = 0; r < 4; ++r) {
            int row = 16 * wr + (lane >> 4) * 4 + r;
            int col = 64 * wc + 16 * t + c16;
            scs[row * 132 + col] = acc[t][r] * 0.125f;
        }
    __syncthreads();

    // ---- softmax: 8 threads per mh-row ----
    {
        int row = tid >> 3, sub = tid & 7;
        float mx = -1e30f;
        #pragma unroll
        for (int i = 0; i < 16; ++i) mx = fmaxf(mx, scs[row * 132 + sub + 8 * i]);
        mx = fmaxf(mx, __shfl_xor(mx, 1));
        mx = fmaxf(mx, __shfl_xor(mx, 2));
        mx = fmaxf(mx, __shfl_xor(mx, 4));
        float e[16], sm = 0.f;
        #pragma unroll
        for (int i = 0; i < 16; ++i) { e[i] = __expf(scs[row * 132 + sub + 8 * i] - mx); sm += e[i]; }
        sm += __shfl_xor(sm, 1);
        sm += __shfl_xor(sm, 2);
        sm += __shfl_xor(sm, 4);
        float rinv = 1.0f / sm;
        #pragma unroll
        for (int i = 0; i < 16; ++i)
            wbuf[row * 136 + sub + 8 * i] = (short)f2bf(e[i] * rinv);
    }
    __syncthreads();

    // ---- phase 2: v~ GEMM, out [32 mh x 512 k], K = s = 128 ----
    f32x4 vacc[16] = {};
    const int hi = tid >> 6;
    for (int s0 = 0; s0 < S_; s0 += 32) {
        #pragma unroll
        for (int c = 0; c < 8; ++c) {   // transposed value staging: Vs[n][ss]
            int n = lane + 64 * c;
            union { ushort u[8]; uint4 v; } tv;
            #pragma unroll
            for (int j = 0; j < 8; ++j)
                tv.u[j] = f2bf(value_in[(s0 + hi * 8 + j) * BD + b * D_ + n]);
            *(uint4*)&Vs[n * 40 + hi * 8] = tv.v;
        }
        __syncthreads();
        bf16x8 a = *(const bf16x8*)&wbuf[(16 * wr + c16) * 136 + s0 + koffs];
        #pragma unroll
        for (int t = 0; t < 16; ++t) {
            bf16x8 vf = *(const bf16x8*)&Vs[(256 * wc + 16 * t + c16) * 40 + koffs];
            vacc[t] = __builtin_amdgcn_mfma_f32_16x16x32_bf16(a, vf, vacc[t], 0, 0, 0);
        }
        __syncthreads();
    }
    #pragma unroll
    for (int t = 0; t < 16; ++t)
        #pragma unroll
        for (int r = 0; r < 4; ++r) {
            int row = 16 * wr + (lane >> 4) * 4 + r;
            int col = 256 * wc + 16 * t + c16;
            vt_ws[((mh0 + row) * B_ + b) * D_ + col] = f2bf(vacc[t][r]);
        }
}

// ---------------------------------------------------------------------------
// Kernel 4: ao[m,b,h*64+d'] = v~[mh,b,:].Wv[m][:,h*64+d'] + bv. grid (H, M).
// ---------------------------------------------------------------------------
__global__ __launch_bounds__(256) void k_aoproj(const ushort* __restrict__ vt_ws,
                                                const float* __restrict__ Wv,
                                                const float* __restrict__ bv,
                                                ushort* __restrict__ ao_ws)
{
    __shared__ __align__(16) short Xs[64 * 40];
    __shared__ __align__(16) short Ws[64 * 40];
    const int h = blockIdx.x, m = blockIdx.y;
    const int mh = m * H_ + h;
    f32x4 acc[4] = {};
    gemm64_bw(vt_ws + mh * B_ * D_, D_, Wv + m * D_ * D_ + h * HD_, D_, D_, Xs, Ws, acc);
    const int lane = threadIdx.x & 63, wv = threadIdx.x >> 6;
    #pragma unroll
    for (int t = 0; t < 4; ++t)
        #pragma unroll
        for (int r = 0; r < 4; ++r) {
            int row = 16 * wv + (lane >> 4) * 4 + r;         // b
            int col = 16 * t + (lane & 15);                  // d' in [0,64)
            ao_ws[(m * B_ + row) * D_ + h * HD_ + col] =
                f2bf(acc[t][r] + bv[m * D_ + h * HD_ + col]);
        }
}

// ---------------------------------------------------------------------------
// Kernel 5: attn_out = ao @ Wo + bo; x = relu([attn_out, prev_state]) -> x_ws
// grid (D/64, M)
// ---------------------------------------------------------------------------
__global__ __launch_bounds__(256) void k_oproj(const ushort* __restrict__ ao_ws,
                                               const float* __restrict__ Wo,
                                               const float* __restrict__ bo,
                                               const float* __restrict__ prev_state,
                                               ushort* __restrict__ x_ws)
{
    __shared__ __align__(16) short Xs[64 * 40];
    __shared__ __align__(16) short Ws[64 * 40];
    const int cb = blockIdx.x, m = blockIdx.y;
    #pragma unroll
    for (int e = 0; e < 2; ++e) {
        int idx = threadIdx.x + e * 256;
        int row = idx >> 3, koff = (idx & 7) * 8;
        const float* pp = prev_state + (m * B_ + row) * D_ + cb * 64 + koff;
        float4 a = *(const float4*)pp, b = *(const float4*)(pp + 4);
        a.x = fmaxf(a.x, 0.f); a.y = fmaxf(a.y, 0.f); a.z = fmaxf(a.z, 0.f); a.w = fmaxf(a.w, 0.f);
        b.x = fmaxf(b.x, 0.f); b.y = fmaxf(b.y, 0.f); b.z = fmaxf(b.z, 0.f); b.w = fmaxf(b.w, 0.f);
        pack8(a, b, (uint4*)&x_ws[(m * B_ + row) * (2 * D_) + D_ + cb * 64 + koff]);
    }
    f32x4 acc[4] = {};
    gemm64_bw(ao_ws + m * B_ * D_, D_, Wo + m * D_ * D_ + cb * 64, D_, D_, Xs, Ws, acc);
    const int lane = threadIdx.x & 63, wv = threadIdx.x >> 6;
    #pragma unroll
    for (int t = 0; t < 4; ++t)
        #pragma unroll
        for (int r = 0; r < 4; ++r) {
            int row = 16 * wv + (lane >> 4) * 4 + r;
            int col = cb * 64 + 16 * t + (lane & 15);
            float v = fmaxf(acc[t][r] + bo[m * D_ + col], 0.0f);
            x_ws[(m * B_ + row) * (2 * D_) + col] = f2bf(v);
        }
}

// ---------------------------------------------------------------------------
// Kernel 6: h = relu(x@W1+b1), hg = relu(x@Wg1+bg1) fused (shared X-tile).
// grid (FF/64, M, 4 g)
// ---------------------------------------------------------------------------
__global__ __launch_bounds__(256) void k_mlp1(const ushort* __restrict__ x_ws,
                                              const float* __restrict__ W1,
                                              const float* __restrict__ b1,
                                              const float* __restrict__ Wg1,
                                              const float* __restrict__ bg1,
                                              ushort* __restrict__ h_ws,
                                              ushort* __restrict__ hg_ws)
{
    __shared__ __align__(16) short Xs[64 * 40];
    __shared__ __align__(16) short Wa[64 * 40];
    __shared__ __align__(16) short Wb[64 * 40];
    const int cb = blockIdx.x, m = blockIdx.y, g = blockIdx.z;
    const int gm = g * M_ + m;
    const float* WA = W1 + gm * 2 * D_ * FF_ + cb * 64;
    const float* WB = Wg1 + gm * 2 * D_ * FF_ + cb * 64;
    const ushort* X = x_ws + m * B_ * 2 * D_;
    const int tid = threadIdx.x, lane = tid & 63, wv = tid >> 6;
    const int c16 = lane & 15, koffs = (lane >> 4) * 8;
    const int xr = tid >> 2, xk = (tid & 3) * 8;
    const int wn = tid & 63, wk = (tid >> 6) * 8;
    f32x4 acc1[4] = {}, acc2[4] = {};
    for (int k0 = 0; k0 < 2 * D_; k0 += 32) {
        *(uint4*)&Xs[xr * 40 + xk] = *(const uint4*)&X[xr * (2 * D_) + k0 + xk];
        const float* wp1 = WA + (k0 + wk) * FF_ + wn;
        const float* wp2 = WB + (k0 + wk) * FF_ + wn;
        union { ushort u[8]; uint4 v; } t1, t2;
        #pragma unroll
        for (int j = 0; j < 8; ++j) { t1.u[j] = f2bf(wp1[j * FF_]); t2.u[j] = f2bf(wp2[j * FF_]); }
        *(uint4*)&Wa[wn * 40 + wk] = t1.v;
        *(uint4*)&Wb[wn * 40 + wk] = t2.v;
        __syncthreads();
        bf16x8 a = *(const bf16x8*)&Xs[(16 * wv + c16) * 40 + koffs];
        #pragma unroll
        for (int t = 0; t < 4; ++t) {
            bf16x8 f1 = *(const bf16x8*)&Wa[(16 * t + c16) * 40 + koffs];
            bf16x8 f2 = *(const bf16x8*)&Wb[(16 * t + c16) * 40 + koffs];
            acc1[t] = __builtin_amdgcn_mfma_f32_16x16x32_bf16(a, f1, acc1[t], 0, 0, 0);
            acc2[t] = __builtin_amdgcn_mfma_f32_16x16x32_bf16(a, f2, acc2[t], 0, 0, 0);
        }
        __syncthreads();
    }
    #pragma unroll
    for (int t = 0; t < 4; ++t)
        #pragma unroll
        for (int r = 0; r < 4; ++r) {
            int row = 16 * wv + (lane >> 4) * 4 + r;
            int col = cb * 64 + 16 * t + c16;
            float v1 = fmaxf(acc1[t][r] + b1[gm * FF_ + col], 0.0f);
            float v2 = fmaxf(acc2[t][r] + bg1[gm * FF_ + col], 0.0f);
            h_ws [(gm * B_ + row) * FF_ + col] = f2bf(v1);
            hg_ws[(gm * B_ + row) * FF_ + col] = f2bf(v2);
        }
}

// ---------------------------------------------------------------------------
// Kernel 7: g = sigmoid(hg . Wg2 + bg2). grid (32) = (g,m).
// ---------------------------------------------------------------------------
__global__ __launch_bounds__(256) void k_gate(const ushort* __restrict__ hg_ws,
                                              const float* __restrict__ Wg2,
                                              const float* __restrict__ bg2,
                                              float* __restrict__ g_ws)
{
    const int gm = blockIdx.x;
    const int tid = threadIdx.x, b = tid >> 2, q = tid & 3;
    const ushort* hp = hg_ws + (gm * B_ + b) * FF_ + q * 256;
    const float* wp = Wg2 + gm * FF_ + q * 256;
    float s = 0.f;
    for (int j = 0; j < 256; j += 8) {
        union { ushort u[8]; uint4 v; } a;
        a.v = *(const uint4*)&hp[j];
        float4 w0 = *(const float4*)&wp[j], w1 = *(const float4*)&wp[j + 4];
        s += bf2f(a.u[0]) * w0.x + bf2f(a.u[1]) * w0.y + bf2f(a.u[2]) * w0.z + bf2f(a.u[3]) * w0.w
           + bf2f(a.u[4]) * w1.x + bf2f(a.u[5]) * w1.y + bf2f(a.u[6]) * w1.z + bf2f(a.u[7]) * w1.w;
    }
    __shared__ float red[256];
    red[b * 4 + q] = s;
    __syncthreads();
    if (tid < 64) {
        float t = red[tid * 4] + red[tid * 4 + 1] + red[tid * 4 + 2] + red[tid * 4 + 3]
                + bg2[gm];
        g_ws[gm * B_ + tid] = 1.0f / (1.0f + __expf(-t));
    }
}

// ---------------------------------------------------------------------------
// Kernel 8: out = tanh(relu(h@W2+b2)); new = g*out + (1-g)*prev; permuted store.
// grid (D/64, M, 4 g). Output slot: g -> (g+1)&3.
// ---------------------------------------------------------------------------
__global__ __launch_bounds__(256) void k_mlp2(const ushort* __restrict__ h_ws,
                                              const float* __restrict__ W2,
                                              const float* __restrict__ b2,
                                              const float* __restrict__ g_ws,
                                              const float* __restrict__ prev_state,
                                              const float* __restrict__ prev_query,
                                              const float* __restrict__ prev_key,
                                              const float* __restrict__ prev_value,
                                              float* __restrict__ outp)
{
    __shared__ __align__(16) short Xs[64 * 40];
    __shared__ __align__(16) short Ws[64 * 40];
    const int cb = blockIdx.x, m = blockIdx.y, g = blockIdx.z;
    const int gm = g * M_ + m;
    f32x4 acc[4] = {};
    gemm64_bw(h_ws + gm * B_ * FF_, FF_, W2 + gm * FF_ * D_ + cb * 64, D_, FF_, Xs, Ws, acc);
    const float* prev = (g == 0) ? prev_query : (g == 1) ? prev_key
                      : (g == 2) ? prev_value : prev_state;
    const int slot = (g + 1) & 3;
    const int lane = threadIdx.x & 63, wv = threadIdx.x >> 6;
    #pragma unroll
    for (int t = 0; t < 4; ++t)
        #pragma unroll
        for (int r = 0; r < 4; ++r) {
            int row = 16 * wv + (lane >> 4) * 4 + r;
            int col = cb * 64 + 16 * t + (lane & 15);
            float v = tanhf(fmaxf(acc[t][r] + b2[gm * D_ + col], 0.0f));
            float gg = g_ws[gm * B_ + row];
            float pv = prev[(m * B_ + row) * D_ + col];
            outp[((slot * M_ + m) * B_ + row) * D_ + col] = gg * v + (1.0f - gg) * pv;
        }
}

// ---------------------------------------------------------------------------
extern "C" void kernel_launch(void* const* d_in, const int* in_sizes, int n_in,
                              void* d_out, int out_size, void* d_ws, size_t ws_size,
                              hipStream_t stream)
{
    (void)in_sizes; (void)n_in; (void)out_size; (void)ws_size;
    const float* prev_state = (const float*)d_in[0];
    const float* prev_query = (const float*)d_in[1];
    const float* prev_key   = (const float*)d_in[2];
    const float* prev_value = (const float*)d_in[3];
    const float* key_in     = (const float*)d_in[4];
    const float* value_in   = (const float*)d_in[5];
    const float* Wq  = (const float*)d_in[6];
    const float* bq  = (const float*)d_in[7];
    const float* Wk  = (const float*)d_in[8];
    const float* Wv  = (const float*)d_in[10];
    const float* bv  = (const float*)d_in[11];
    const float* Wo  = (const float*)d_in[12];
    const float* bo  = (const float*)d_in[13];
    const float* W1  = (const float*)d_in[14];
    const float* b1  = (const float*)d_in[15];
    const float* W2  = (const float*)d_in[16];
    const float* b2  = (const float*)d_in[17];
    const float* Wg1 = (const float*)d_in[18];
    const float* bg1 = (const float*)d_in[19];
    const float* Wg2 = (const float*)d_in[20];
    const float* bg2 = (const float*)d_in[21];
    float* outp = (float*)d_out;

    char* ws = (char*)d_ws;
    ushort* q_ws  = (ushort*)(ws);                        // 512 KB
    ushort* ao_ws = (ushort*)(ws + (512u << 10));         // 512 KB
    ushort* x_ws  = (ushort*)(ws + (1024u << 10));        // 1 MB
    ushort* qt_ws = (ushort*)(ws + (2048u << 10));        // 4 MB (later reused as h_ws)
    ushort* vt_ws = (ushort*)(ws + (6144u << 10));        // 4 MB (later reused as hg_ws)
    ushort* h_ws  = qt_ws;                                // overlay: qt dead after k_attn2
    ushort* hg_ws = vt_ws;                                // overlay: vt dead after k_aoproj
    float*  g_ws  = (float*) (ws + (10240u << 10));       // 8 KB

    k_qproj <<<dim3(8, 8), 256, 0, stream>>>(prev_query, Wq, bq, q_ws);
    k_qtilde<<<dim3(8, 8, 8), 256, 0, stream>>>(q_ws, Wk, qt_ws);
    k_attn2 <<<dim3(2, 64), 256, 0, stream>>>(key_in, value_in, qt_ws, vt_ws);
    k_aoproj<<<dim3(8, 8), 256, 0, stream>>>(vt_ws, Wv, bv, ao_ws);
    k_oproj <<<dim3(8, 8), 256, 0, stream>>>(ao_ws, Wo, bo, prev_state, x_ws);
    k_mlp1  <<<dim3(16, 8, 4), 256, 0, stream>>>(x_ws, W1, b1, Wg1, bg1, h_ws, hg_ws);
    k_gate  <<<dim3(32), 256, 0, stream>>>(hg_ws, Wg2, bg2, g_ws);
    k_mlp2  <<<dim3(8, 8, 4), 256, 0, stream>>>(h_ws, W2, b2, g_ws,
                                                prev_state, prev_query, prev_key, prev_value, outp);
}